// Round 8
// baseline (579.858 us; speedup 1.0000x reference)
//
#include <hip/hip_runtime.h>
#include <hip/hip_bf16.h>
#include <math.h>

// Problem constants
#define BATCH 1024
#define NREAL 784
#define NPAD  896      // 7*128 zero-padded graph dim
#define C1D   32
#define C2D   32
#define HDIM  512
#define NCLS  10
#define KFC   25088    // 784*32

#define KS_FC 14       // split-K fc1: K=25088 -> 1792/slice, 56 iters (EVEN)
#define G1_ITERS 28    // K=896 full reduction in the fused G1 kernel (EVEN)

#define BK 32

using bf16x8  = __attribute__((ext_vector_type(8))) __bf16;
using floatx4 = __attribute__((ext_vector_type(4))) float;

__device__ __forceinline__ float elu_f(float t) {
    return t > 0.f ? t : (__expf(t) - 1.f);
}

// LDS-only barrier: waits ds ops but leaves global loads (vmcnt) in flight.
__device__ __forceinline__ void wg_barrier_lds() {
    asm volatile("s_waitcnt lgkmcnt(0)\n\ts_barrier" ::: "memory");
}

// ---------------------------------------------------------------------------
// r5 BT-GEMM (best measured core, 95.5us @ G3): register-staged pipeline +
// XOR-swizzled LDS (conflict-free, verified SQ_LDS_BANK_CONFLICT=0).
// C[row][col] = sum_k A[row][k]*Bm[col][k]; kIters MUST be even.
// 128x128 tile, 4 waves (2x2 of 64x64), mfma 16x16x32 bf16.
// MODE 1: elu(acc+bias[col&31]) -> bf16 outH[(col>>5)*KFC+row*32+(col&31)],
//         masked to row<784                                           (G3)
// MODE 2: fp32 partial store outF[z*sliceStride + row*ldc + col]       (G4)
// ---------------------------------------------------------------------------
template<int MODE>
__launch_bounds__(256)
__global__ void gemm_bt(const __hip_bfloat16* __restrict__ A, int lda,
                        const __hip_bfloat16* __restrict__ Bm, int ldb,
                        int kIters, int kPerZ, size_t sliceStride,
                        float* __restrict__ outF, int ldc,
                        __hip_bfloat16* __restrict__ outH,
                        const float* __restrict__ bias)
{
    __shared__ __align__(16) __hip_bfloat16 As[2][128 * BK];
    __shared__ __align__(16) __hip_bfloat16 Bs[2][128 * BK];

    const int tid  = threadIdx.x;
    const int lane = tid & 63;
    const int wave = tid >> 6;
    const int wi = wave >> 1, wj = wave & 1;

    const int m0 = blockIdx.y * 128;
    const int n0 = blockIdx.x * 128;
    const int kBase = blockIdx.z * kPerZ;

    const int rowInChunk = lane >> 2;
    const int kOff8 = (lane & 3) * 8;

    const __hip_bfloat16* aSrc0 = A  + (size_t)(m0 + (wave * 2 + 0) * 16 + rowInChunk) * lda + kBase + kOff8;
    const __hip_bfloat16* aSrc1 = A  + (size_t)(m0 + (wave * 2 + 1) * 16 + rowInChunk) * lda + kBase + kOff8;
    const __hip_bfloat16* bSrc0 = Bm + (size_t)(n0 + (wave * 2 + 0) * 16 + rowInChunk) * ldb + kBase + kOff8;
    const __hip_bfloat16* bSrc1 = Bm + (size_t)(n0 + (wave * 2 + 1) * 16 + rowInChunk) * ldb + kBase + kOff8;

    const int wSlot = (((lane & 3) + ((lane >> 3) & 3)) & 3) * 8;
    const int ldsW0 = (wave * 2 + 0) * 512 + rowInChunk * 32 + wSlot;
    const int ldsW1 = ldsW0 + 512;

    const int rSlot = ((((lane >> 4) + (((lane & 15) >> 1) & 3)) & 3)) * 8;
    const int rRow  = lane & 15;

    floatx4 acc[4][4];
    const floatx4 zero4 = {0.f, 0.f, 0.f, 0.f};
    #pragma unroll
    for (int i = 0; i < 4; i++)
        #pragma unroll
        for (int j = 0; j < 4; j++) acc[i][j] = zero4;

    int4 aAe0, aAe1, bAe0, bAe1;   // even stages
    int4 aAo0, aAo1, bAo0, bAo1;   // odd stages

    aAe0 = *(const int4*)aSrc0; aAe1 = *(const int4*)aSrc1;
    bAe0 = *(const int4*)bSrc0; bAe1 = *(const int4*)bSrc1;
    aSrc0 += BK; aSrc1 += BK; bSrc0 += BK; bSrc1 += BK;
    aAo0 = *(const int4*)aSrc0; aAo1 = *(const int4*)aSrc1;
    bAo0 = *(const int4*)bSrc0; bAo1 = *(const int4*)bSrc1;
    aSrc0 += BK; aSrc1 += BK; bSrc0 += BK; bSrc1 += BK;

    *(int4*)(&As[0][ldsW0]) = aAe0;
    *(int4*)(&As[0][ldsW1]) = aAe1;
    *(int4*)(&Bs[0][ldsW0]) = bAe0;
    *(int4*)(&Bs[0][ldsW1]) = bAe1;
    wg_barrier_lds();

    for (int kt = 0; kt < kIters; kt += 2) {
        const bool more = (kt + 2 < kIters);

        {   // u = 0: compute stage kt from buf 0
            bf16x8 af[4], bfr[4];
            #pragma unroll
            for (int mi = 0; mi < 4; mi++)
                af[mi] = *(const bf16x8*)(&As[0][(wi * 64 + mi * 16 + rRow) * BK + rSlot]);
            #pragma unroll
            for (int nj = 0; nj < 4; nj++)
                bfr[nj] = *(const bf16x8*)(&Bs[0][(wj * 64 + nj * 16 + rRow) * BK + rSlot]);

            if (more) {
                aAe0 = *(const int4*)aSrc0; aAe1 = *(const int4*)aSrc1;
                bAe0 = *(const int4*)bSrc0; bAe1 = *(const int4*)bSrc1;
                aSrc0 += BK; aSrc1 += BK; bSrc0 += BK; bSrc1 += BK;
            }
            *(int4*)(&As[1][ldsW0]) = aAo0;
            *(int4*)(&As[1][ldsW1]) = aAo1;
            *(int4*)(&Bs[1][ldsW0]) = bAo0;
            *(int4*)(&Bs[1][ldsW1]) = bAo1;

            #pragma unroll
            for (int mi = 0; mi < 4; mi++)
                #pragma unroll
                for (int nj = 0; nj < 4; nj++)
                    acc[mi][nj] = __builtin_amdgcn_mfma_f32_16x16x32_bf16(af[mi], bfr[nj], acc[mi][nj], 0, 0, 0);

            wg_barrier_lds();
        }

        {   // u = 1: compute stage kt+1 from buf 1
            bf16x8 af[4], bfr[4];
            #pragma unroll
            for (int mi = 0; mi < 4; mi++)
                af[mi] = *(const bf16x8*)(&As[1][(wi * 64 + mi * 16 + rRow) * BK + rSlot]);
            #pragma unroll
            for (int nj = 0; nj < 4; nj++)
                bfr[nj] = *(const bf16x8*)(&Bs[1][(wj * 64 + nj * 16 + rRow) * BK + rSlot]);

            if (more) {
                aAo0 = *(const int4*)aSrc0; aAo1 = *(const int4*)aSrc1;
                bAo0 = *(const int4*)bSrc0; bAo1 = *(const int4*)bSrc1;
                aSrc0 += BK; aSrc1 += BK; bSrc0 += BK; bSrc1 += BK;
                *(int4*)(&As[0][ldsW0]) = aAe0;
                *(int4*)(&As[0][ldsW1]) = aAe1;
                *(int4*)(&Bs[0][ldsW0]) = bAe0;
                *(int4*)(&Bs[0][ldsW1]) = bAe1;
            }

            #pragma unroll
            for (int mi = 0; mi < 4; mi++)
                #pragma unroll
                for (int nj = 0; nj < 4; nj++)
                    acc[mi][nj] = __builtin_amdgcn_mfma_f32_16x16x32_bf16(af[mi], bfr[nj], acc[mi][nj], 0, 0, 0);

            wg_barrier_lds();
        }
    }

    // epilogue: C/D layout col=lane&15, row=(lane>>4)*4+reg  [verified m89/m91]
    #pragma unroll
    for (int mi = 0; mi < 4; mi++) {
        #pragma unroll
        for (int nj = 0; nj < 4; nj++) {
            #pragma unroll
            for (int r = 0; r < 4; r++) {
                const int row = m0 + wi * 64 + mi * 16 + (lane >> 4) * 4 + r;
                const int col = n0 + wj * 64 + nj * 16 + (lane & 15);
                const float v = acc[mi][nj][r];
                if (MODE == 1) {
                    if (row < NREAL) {
                        const int c = col & 31, b = col >> 5;
                        const float t = elu_f(v + bias[c]);
                        outH[(size_t)b * KFC + row * 32 + c] = __float2bfloat16(t);
                    }
                } else {
                    outF[(size_t)blockIdx.z * sliceStride + (size_t)row * ldc + col] = v;
                }
            }
        }
    }
}

// ---------------------------------------------------------------------------
// FUSED G1 + layer-1: one 64(b) x 64(n) tile per block, full K=896 (28 iters,
// r5-style reg-staged swizzled staging, 1 chunk/wave/matrix). Y-tile stays in
// LDS; epilogue computes T[(b*32+c)][n] = sum_c1 elu(Y*w1+b1)[c1]*W2[c1][c]
// and stores coalesced bf16x2. Kills the 51 MB Ypart round-trip.
// Grid: (NPAD/64=14, BATCH/64=16). Padded n>=784 cols produce finite garbage
// that G3 multiplies by A's zero k-columns -> exact.
// ---------------------------------------------------------------------------
__launch_bounds__(256)
__global__ void g1_layer1(const __hip_bfloat16* __restrict__ Xbf,  // [1024][896]
                          const __hip_bfloat16* __restrict__ Ar,   // [896][896]
                          const float* __restrict__ w1, const float* __restrict__ b1,
                          const float* __restrict__ w2,
                          __hip_bfloat16* __restrict__ Tt)         // [32768][896]
{
    __shared__ __align__(16) __hip_bfloat16 As[2][64 * BK];   // 4 KB each
    __shared__ __align__(16) __hip_bfloat16 Bs[2][64 * BK];
    __shared__ float Ys[64 * 65];                             // pad -> 2-way max
    __shared__ __align__(16) float sW2[C1D * C2D];
    __shared__ float sw1[C1D], sb1[C1D];

    const int tid  = threadIdx.x;
    const int lane = tid & 63;
    const int wave = tid >> 6;
    const int wi = wave >> 1, wj = wave & 1;

    const int n0 = blockIdx.x * 64;
    const int m0 = blockIdx.y * 64;

    // parameter staging (covered by first wg_barrier_lds)
    for (int i = tid; i < C1D * C2D; i += 256) sW2[i] = w2[i];
    if (tid < C1D) { sw1[tid] = w1[tid]; sb1[tid] = b1[tid]; }

    const int rowInChunk = lane >> 2;
    const int kOff8 = (lane & 3) * 8;
    const __hip_bfloat16* aSrc = Xbf + (size_t)(m0 + wave * 16 + rowInChunk) * NPAD + kOff8;
    const __hip_bfloat16* bSrc = Ar  + (size_t)(n0 + wave * 16 + rowInChunk) * NPAD + kOff8;

    const int wSlot = (((lane & 3) + ((lane >> 3) & 3)) & 3) * 8;
    const int ldsW = wave * 512 + rowInChunk * 32 + wSlot;
    const int rSlot = ((((lane >> 4) + (((lane & 15) >> 1) & 3)) & 3)) * 8;
    const int rRow  = lane & 15;

    floatx4 acc[2][2];
    const floatx4 zero4 = {0.f, 0.f, 0.f, 0.f};
    #pragma unroll
    for (int i = 0; i < 2; i++)
        #pragma unroll
        for (int j = 0; j < 2; j++) acc[i][j] = zero4;

    int4 aE, bE, aO, bO;
    aE = *(const int4*)aSrc; bE = *(const int4*)bSrc; aSrc += BK; bSrc += BK;
    aO = *(const int4*)aSrc; bO = *(const int4*)bSrc; aSrc += BK; bSrc += BK;

    *(int4*)(&As[0][ldsW]) = aE;
    *(int4*)(&Bs[0][ldsW]) = bE;
    wg_barrier_lds();

    for (int kt = 0; kt < G1_ITERS; kt += 2) {
        const bool more = (kt + 2 < G1_ITERS);
        {   // u=0
            bf16x8 af[2], bfr[2];
            #pragma unroll
            for (int mi = 0; mi < 2; mi++)
                af[mi] = *(const bf16x8*)(&As[0][(wi * 32 + mi * 16 + rRow) * BK + rSlot]);
            #pragma unroll
            for (int nj = 0; nj < 2; nj++)
                bfr[nj] = *(const bf16x8*)(&Bs[0][(wj * 32 + nj * 16 + rRow) * BK + rSlot]);
            if (more) { aE = *(const int4*)aSrc; bE = *(const int4*)bSrc; aSrc += BK; bSrc += BK; }
            *(int4*)(&As[1][ldsW]) = aO;
            *(int4*)(&Bs[1][ldsW]) = bO;
            #pragma unroll
            for (int mi = 0; mi < 2; mi++)
                #pragma unroll
                for (int nj = 0; nj < 2; nj++)
                    acc[mi][nj] = __builtin_amdgcn_mfma_f32_16x16x32_bf16(af[mi], bfr[nj], acc[mi][nj], 0, 0, 0);
            wg_barrier_lds();
        }
        {   // u=1
            bf16x8 af[2], bfr[2];
            #pragma unroll
            for (int mi = 0; mi < 2; mi++)
                af[mi] = *(const bf16x8*)(&As[1][(wi * 32 + mi * 16 + rRow) * BK + rSlot]);
            #pragma unroll
            for (int nj = 0; nj < 2; nj++)
                bfr[nj] = *(const bf16x8*)(&Bs[1][(wj * 32 + nj * 16 + rRow) * BK + rSlot]);
            if (more) {
                aO = *(const int4*)aSrc; bO = *(const int4*)bSrc; aSrc += BK; bSrc += BK;
                *(int4*)(&As[0][ldsW]) = aE;
                *(int4*)(&Bs[0][ldsW]) = bE;
            }
            #pragma unroll
            for (int mi = 0; mi < 2; mi++)
                #pragma unroll
                for (int nj = 0; nj < 2; nj++)
                    acc[mi][nj] = __builtin_amdgcn_mfma_f32_16x16x32_bf16(af[mi], bfr[nj], acc[mi][nj], 0, 0, 0);
            wg_barrier_lds();
        }
    }

    // dump Y tile to LDS (C/D layout -> [b_local][n_local], pad 65)
    #pragma unroll
    for (int mi = 0; mi < 2; mi++)
        #pragma unroll
        for (int nj = 0; nj < 2; nj++)
            #pragma unroll
            for (int r = 0; r < 4; r++) {
                const int bl = wi * 32 + mi * 16 + (lane >> 4) * 4 + r;
                const int nl = wj * 32 + nj * 16 + (lane & 15);
                Ys[bl * 65 + nl] = acc[mi][nj][r];
            }
    __syncthreads();

    // epilogue: thread owns (n_l, n_l+1) x 8 b's
    const int n_l = (tid & 31) * 2;
    const int bq  = tid >> 5;                 // 0..7
    #pragma unroll 1
    for (int i = 0; i < 8; i++) {
        const int bl = bq * 8 + i;
        const float y0 = Ys[bl * 65 + n_l];
        const float y1 = Ys[bl * 65 + n_l + 1];
        float t0[C2D], t1[C2D];
        #pragma unroll
        for (int c = 0; c < C2D; c++) { t0[c] = 0.f; t1[c] = 0.f; }
        #pragma unroll
        for (int c1 = 0; c1 < C1D; c1++) {
            const float h0 = elu_f(y0 * sw1[c1] + sb1[c1]);
            const float h1 = elu_f(y1 * sw1[c1] + sb1[c1]);
            const float* wr = sW2 + c1 * C2D;
            #pragma unroll
            for (int c = 0; c < C2D; c++) { t0[c] += h0 * wr[c]; t1[c] += h1 * wr[c]; }
        }
        const int bg = m0 + bl;
        #pragma unroll
        for (int c = 0; c < C2D; c++) {
            __hip_bfloat162 pv;
            pv.x = __float2bfloat16(t0[c]);
            pv.y = __float2bfloat16(t1[c]);
            *(__hip_bfloat162*)(Tt + (size_t)(bg * 32 + c) * NPAD + n0 + n_l) = pv;
        }
    }
}

// ---------------------------------------------------------------------------
// convXA: x -> Xbf row-major [1024][896] bf16 (zero k-pad)
//         a -> Ar row-major [896][896] bf16 (zero pad both dims)
// ---------------------------------------------------------------------------
__global__ void convXA(const float* __restrict__ x, const float* __restrict__ a,
                       __hip_bfloat16* __restrict__ Xbf, __hip_bfloat16* __restrict__ Ar)
{
    int idx = blockIdx.x * 256 + threadIdx.x;
    if (idx < BATCH * NPAD) {
        const int m = idx % NPAD, b = idx / NPAD;
        const float v = (m < NREAL) ? x[(size_t)b * NREAL + m] : 0.f;
        Xbf[idx] = __float2bfloat16(v);
    } else {
        idx -= BATCH * NPAD;
        if (idx < NPAD * NPAD) {
            const int m = idx % NPAD, n = idx / NPAD;
            const float v = (m < NREAL && n < NREAL) ? a[(size_t)n * NREAL + m] : 0.f;
            Ar[idx] = __float2bfloat16(v);
        }
    }
}

// wf1 [25088][512] fp32 -> Wt row-major bf16 [512][25088]
__global__ void convW(const float* __restrict__ wf1, __hip_bfloat16* __restrict__ Wt) {
    __shared__ float tile[32][33];
    const int k0 = blockIdx.x * 32, h0 = blockIdx.y * 32;
    const int tx = threadIdx.x, ty = threadIdx.y;  // (32,8)
    #pragma unroll
    for (int i = 0; i < 4; i++)
        tile[ty * 4 + i][tx] = wf1[(size_t)(k0 + ty * 4 + i) * HDIM + h0 + tx];
    __syncthreads();
    #pragma unroll
    for (int i = 0; i < 4; i++)
        Wt[(size_t)(h0 + ty * 4 + i) * KFC + k0 + tx] = __float2bfloat16(tile[tx][ty * 4 + i]);
}

// ---------------------------------------------------------------------------
// fc1 reduce (split-K partials) + relu + fc2 + softmax, fused.
// ---------------------------------------------------------------------------
__global__ void fc2_softmax(const float* __restrict__ part, const float* __restrict__ bf1,
                            const float* __restrict__ wf2, const float* __restrict__ bf2,
                            float* __restrict__ out)
{
    __shared__ float sW[HDIM * NCLS];
    __shared__ float sb[NCLS];
    const int tid = threadIdx.x;                 // 256
    for (int i = tid; i < HDIM * NCLS; i += 256) sW[i] = wf2[i];
    if (tid < NCLS) sb[tid] = bf2[tid];
    __syncthreads();

    const int lane = tid & 63, wave = tid >> 6;
    const int b = blockIdx.x * 4 + wave;

    float acc[NCLS];
    #pragma unroll
    for (int c = 0; c < NCLS; c++) acc[c] = 0.f;
    #pragma unroll
    for (int q = 0; q < 8; q++) {
        const int h = q * 64 + lane;
        float hv = bf1[h];
        #pragma unroll
        for (int z = 0; z < KS_FC; z++)
            hv += part[(size_t)z * (BATCH * HDIM) + (size_t)b * HDIM + h];
        hv = hv > 0.f ? hv : 0.f;
        #pragma unroll
        for (int c = 0; c < NCLS; c++) acc[c] += hv * sW[h * NCLS + c];
    }
    #pragma unroll
    for (int c = 0; c < NCLS; c++) {
        #pragma unroll
        for (int off = 32; off >= 1; off >>= 1) acc[c] += __shfl_down(acc[c], off);
    }
    if (lane == 0) {
        float mx = -1e30f;
        #pragma unroll
        for (int c = 0; c < NCLS; c++) { acc[c] += sb[c]; mx = fmaxf(mx, acc[c]); }
        float e[NCLS], s = 0.f;
        #pragma unroll
        for (int c = 0; c < NCLS; c++) { e[c] = __expf(acc[c] - mx); s += e[c]; }
        const float inv = 1.f / s;
        #pragma unroll
        for (int c = 0; c < NCLS; c++) out[(size_t)b * NCLS + c] = e[c] * inv;
    }
}

// ---------------------------------------------------------------------------
// Workspace layout (peak ~113.5 MB)
//   h2f   [0,          51380224)  bf16 1024x25088  (written G3, read G4)
//   Tt    [51380224,  110100480)  bf16 32768x896   (dead after G3)
//     Wt   [51380224, 77070336)   bf16 512x25088 — overlay after G3
//     part [77070336, 106430464)  f32 14x1024x512 — overlay after G3
//   Ar    [110100480, 111706112)  bf16 896x896
//   Xbf   [111706112, 113541120)  bf16 1024x896
// ---------------------------------------------------------------------------
extern "C" void kernel_launch(void* const* d_in, const int* in_sizes, int n_in,
                              void* d_out, int out_size, void* d_ws, size_t ws_size,
                              hipStream_t stream)
{
    const float* x   = (const float*)d_in[0];
    const float* a   = (const float*)d_in[1];
    const float* w1  = (const float*)d_in[2];
    const float* b1  = (const float*)d_in[3];
    const float* w2  = (const float*)d_in[4];
    const float* b2  = (const float*)d_in[5];
    const float* wf1 = (const float*)d_in[6];
    const float* bf1 = (const float*)d_in[7];
    const float* wf2 = (const float*)d_in[8];
    const float* bf2 = (const float*)d_in[9];
    float* out = (float*)d_out;

    char* ws = (char*)d_ws;
    __hip_bfloat16* h2f  = (__hip_bfloat16*)(ws + 0);
    __hip_bfloat16* Tt   = (__hip_bfloat16*)(ws + 51380224);
    __hip_bfloat16* Wt   = (__hip_bfloat16*)(ws + 51380224);  // overlay (post-G3)
    float*          part = (float*)(ws + 77070336);           // overlay (post-G3)
    __hip_bfloat16* Ar   = (__hip_bfloat16*)(ws + 110100480);
    __hip_bfloat16* Xbf  = (__hip_bfloat16*)(ws + 111706112);

    // 1) convert x and a (row-major bf16, zero-padded)
    convXA<<<(BATCH * NPAD + NPAD * NPAD + 255) / 256, 256, 0, stream>>>(x, a, Xbf, Ar);

    // 2) fused G1 + layer-1 -> Tt (full-K, 14x16 = 224 blocks)
    g1_layer1<<<dim3(NPAD / 64, BATCH / 64), 256, 0, stream>>>(Xbf, Ar, w1, b1, w2, Tt);

    // 3) G3: h2 = elu(A @ T + b2)  (M=896, N=32768, K=896 -> 1792 blocks, 28 iters)
    gemm_bt<1><<<dim3((BATCH * 32) / 128, NPAD / 128, 1), 256, 0, stream>>>(
        Ar, NPAD, Tt, NPAD, NPAD / BK, 0, 0, nullptr, 0, h2f, b2);

    // 4) wf1 -> Wt row-major (into dead-Tt region)
    convW<<<dim3(KFC / 32, HDIM / 32), dim3(32, 8), 0, stream>>>(wf1, Wt);

    // 5) G4: fc1 partials, split-K=14 (448 blocks, 56 iters)
    gemm_bt<2><<<dim3(HDIM / 128, BATCH / 128, KS_FC), 256, 0, stream>>>(
        h2f, KFC, Wt, KFC, (KFC / KS_FC) / BK, KFC / KS_FC,
        (size_t)BATCH * HDIM, part, HDIM, nullptr, nullptr);

    // 6) fc1 reduce + relu + fc2 + softmax
    fc2_softmax<<<BATCH / 4, 256, 0, stream>>>(part, bf1, wf2, bf2, out);
}

// Round 9
// 304.422 us; speedup vs baseline: 1.9048x; 1.9048x over previous
//
#include <hip/hip_runtime.h>
#include <hip/hip_bf16.h>
#include <math.h>

// Problem constants
#define BATCH 1024
#define NREAL 784
#define NPAD  896      // 7*128 zero-padded graph dim
#define C1D   32
#define C2D   32
#define HDIM  512
#define NCLS  10
#define KFC   25088    // 784*32

#define KS_G1 7        // split-K G1: K=896 -> 128/slice, 4 iters (EVEN)
#define KS_FC 14       // split-K fc1: K=25088 -> 1792/slice, 56 iters (EVEN)

#define BK 32

using bf16x8  = __attribute__((ext_vector_type(8))) __bf16;
using floatx4 = __attribute__((ext_vector_type(4))) float;

__device__ __forceinline__ float elu_f(float t) {
    return t > 0.f ? t : (__expf(t) - 1.f);
}

// LDS-only barrier: waits ds ops but leaves global loads (vmcnt) in flight.
__device__ __forceinline__ void wg_barrier_lds() {
    asm volatile("s_waitcnt lgkmcnt(0)\n\ts_barrier" ::: "memory");
}

// ---------------------------------------------------------------------------
// r5 BT-GEMM (proven core): register-staged pipeline + XOR-swizzled LDS
// (SQ_LDS_BANK_CONFLICT=0 verified). C[row][col] = sum_k A[row][k]*Bm[col][k].
// kIters MUST be even. 128x128 tile, 4 waves (2x2 of 64x64), mfma 16x16x32.
// MODE 2: fp32 partial store outF[z*sliceStride + row*ldc + col]   (G1, G4)
// ---------------------------------------------------------------------------
template<int MODE>
__launch_bounds__(256)
__global__ void gemm_bt(const __hip_bfloat16* __restrict__ A, int lda,
                        const __hip_bfloat16* __restrict__ Bm, int ldb,
                        int kIters, int kPerZ, size_t sliceStride,
                        float* __restrict__ outF, int ldc)
{
    __shared__ __align__(16) __hip_bfloat16 As[2][128 * BK];
    __shared__ __align__(16) __hip_bfloat16 Bs[2][128 * BK];

    const int tid  = threadIdx.x;
    const int lane = tid & 63;
    const int wave = tid >> 6;
    const int wi = wave >> 1, wj = wave & 1;

    const int m0 = blockIdx.y * 128;
    const int n0 = blockIdx.x * 128;
    const int kBase = blockIdx.z * kPerZ;

    const int rowInChunk = lane >> 2;
    const int kOff8 = (lane & 3) * 8;

    const __hip_bfloat16* aSrc0 = A  + (size_t)(m0 + (wave * 2 + 0) * 16 + rowInChunk) * lda + kBase + kOff8;
    const __hip_bfloat16* aSrc1 = A  + (size_t)(m0 + (wave * 2 + 1) * 16 + rowInChunk) * lda + kBase + kOff8;
    const __hip_bfloat16* bSrc0 = Bm + (size_t)(n0 + (wave * 2 + 0) * 16 + rowInChunk) * ldb + kBase + kOff8;
    const __hip_bfloat16* bSrc1 = Bm + (size_t)(n0 + (wave * 2 + 1) * 16 + rowInChunk) * ldb + kBase + kOff8;

    const int wSlot = (((lane & 3) + ((lane >> 3) & 3)) & 3) * 8;
    const int ldsW0 = (wave * 2 + 0) * 512 + rowInChunk * 32 + wSlot;
    const int ldsW1 = ldsW0 + 512;

    const int rSlot = ((((lane >> 4) + (((lane & 15) >> 1) & 3)) & 3)) * 8;
    const int rRow  = lane & 15;

    floatx4 acc[4][4];
    const floatx4 zero4 = {0.f, 0.f, 0.f, 0.f};
    #pragma unroll
    for (int i = 0; i < 4; i++)
        #pragma unroll
        for (int j = 0; j < 4; j++) acc[i][j] = zero4;

    int4 aAe0, aAe1, bAe0, bAe1;   // even stages
    int4 aAo0, aAo1, bAo0, bAo1;   // odd stages

    aAe0 = *(const int4*)aSrc0; aAe1 = *(const int4*)aSrc1;
    bAe0 = *(const int4*)bSrc0; bAe1 = *(const int4*)bSrc1;
    aSrc0 += BK; aSrc1 += BK; bSrc0 += BK; bSrc1 += BK;
    aAo0 = *(const int4*)aSrc0; aAo1 = *(const int4*)aSrc1;
    bAo0 = *(const int4*)bSrc0; bAo1 = *(const int4*)bSrc1;
    aSrc0 += BK; aSrc1 += BK; bSrc0 += BK; bSrc1 += BK;

    *(int4*)(&As[0][ldsW0]) = aAe0;
    *(int4*)(&As[0][ldsW1]) = aAe1;
    *(int4*)(&Bs[0][ldsW0]) = bAe0;
    *(int4*)(&Bs[0][ldsW1]) = bAe1;
    wg_barrier_lds();

    for (int kt = 0; kt < kIters; kt += 2) {
        const bool more = (kt + 2 < kIters);

        {   // u = 0
            bf16x8 af[4], bfr[4];
            #pragma unroll
            for (int mi = 0; mi < 4; mi++)
                af[mi] = *(const bf16x8*)(&As[0][(wi * 64 + mi * 16 + rRow) * BK + rSlot]);
            #pragma unroll
            for (int nj = 0; nj < 4; nj++)
                bfr[nj] = *(const bf16x8*)(&Bs[0][(wj * 64 + nj * 16 + rRow) * BK + rSlot]);

            if (more) {
                aAe0 = *(const int4*)aSrc0; aAe1 = *(const int4*)aSrc1;
                bAe0 = *(const int4*)bSrc0; bAe1 = *(const int4*)bSrc1;
                aSrc0 += BK; aSrc1 += BK; bSrc0 += BK; bSrc1 += BK;
            }
            *(int4*)(&As[1][ldsW0]) = aAo0;
            *(int4*)(&As[1][ldsW1]) = aAo1;
            *(int4*)(&Bs[1][ldsW0]) = bAo0;
            *(int4*)(&Bs[1][ldsW1]) = bAo1;

            #pragma unroll
            for (int mi = 0; mi < 4; mi++)
                #pragma unroll
                for (int nj = 0; nj < 4; nj++)
                    acc[mi][nj] = __builtin_amdgcn_mfma_f32_16x16x32_bf16(af[mi], bfr[nj], acc[mi][nj], 0, 0, 0);

            wg_barrier_lds();
        }

        {   // u = 1
            bf16x8 af[4], bfr[4];
            #pragma unroll
            for (int mi = 0; mi < 4; mi++)
                af[mi] = *(const bf16x8*)(&As[1][(wi * 64 + mi * 16 + rRow) * BK + rSlot]);
            #pragma unroll
            for (int nj = 0; nj < 4; nj++)
                bfr[nj] = *(const bf16x8*)(&Bs[1][(wj * 64 + nj * 16 + rRow) * BK + rSlot]);

            if (more) {
                aAo0 = *(const int4*)aSrc0; aAo1 = *(const int4*)aSrc1;
                bAo0 = *(const int4*)bSrc0; bAo1 = *(const int4*)bSrc1;
                aSrc0 += BK; aSrc1 += BK; bSrc0 += BK; bSrc1 += BK;
                *(int4*)(&As[0][ldsW0]) = aAe0;
                *(int4*)(&As[0][ldsW1]) = aAe1;
                *(int4*)(&Bs[0][ldsW0]) = bAe0;
                *(int4*)(&Bs[0][ldsW1]) = bAe1;
            }

            #pragma unroll
            for (int mi = 0; mi < 4; mi++)
                #pragma unroll
                for (int nj = 0; nj < 4; nj++)
                    acc[mi][nj] = __builtin_amdgcn_mfma_f32_16x16x32_bf16(af[mi], bfr[nj], acc[mi][nj], 0, 0, 0);

            wg_barrier_lds();
        }
    }

    // epilogue: C/D layout col=lane&15, row=(lane>>4)*4+reg
    #pragma unroll
    for (int mi = 0; mi < 4; mi++) {
        #pragma unroll
        for (int nj = 0; nj < 4; nj++) {
            #pragma unroll
            for (int r = 0; r < 4; r++) {
                const int row = m0 + wi * 64 + mi * 16 + (lane >> 4) * 4 + r;
                const int col = n0 + wj * 64 + nj * 16 + (lane & 15);
                outF[(size_t)blockIdx.z * sliceStride + (size_t)row * ldc + col] = acc[mi][nj][r];
            }
        }
    }
}

// ---------------------------------------------------------------------------
// WIDE BT-GEMM for G3: block 128(m) x 256(n), 4 waves 2x2, wave-tile 64x128.
// Same r5 staging/swizzle; 1.33x more FLOP per LDS-read-byte (42.7 vs 32) to
// attack the measured DS-issue limit (512 cyc/block-iter at 64x64).
// Epilogue (G3): elu(acc+bias[col&31]) -> bf16 outH[(col>>5)*KFC+row*32+c],
// masked to row<784.
// ---------------------------------------------------------------------------
__launch_bounds__(256, 2)
__global__ void gemm_w(const __hip_bfloat16* __restrict__ A, int lda,
                       const __hip_bfloat16* __restrict__ Bm, int ldb,
                       int kIters,
                       __hip_bfloat16* __restrict__ outH,
                       const float* __restrict__ bias)
{
    __shared__ __align__(16) __hip_bfloat16 As[2][128 * BK];   //  8 KB each
    __shared__ __align__(16) __hip_bfloat16 Bs[2][256 * BK];   // 16 KB each

    const int tid  = threadIdx.x;
    const int lane = tid & 63;
    const int wave = tid >> 6;
    const int wi = wave >> 1, wj = wave & 1;

    const int m0 = blockIdx.y * 128;
    const int n0 = blockIdx.x * 256;

    const int rowInChunk = lane >> 2;
    const int kOff8 = (lane & 3) * 8;

    // staging: wave stages A chunks {2w,2w+1}, B chunks {4w..4w+3}
    const __hip_bfloat16* aSrc0 = A  + (size_t)(m0 + (wave * 2 + 0) * 16 + rowInChunk) * lda + kOff8;
    const __hip_bfloat16* aSrc1 = A  + (size_t)(m0 + (wave * 2 + 1) * 16 + rowInChunk) * lda + kOff8;
    const __hip_bfloat16* bSrc0 = Bm + (size_t)(n0 + (wave * 4 + 0) * 16 + rowInChunk) * ldb + kOff8;
    const __hip_bfloat16* bSrc1 = Bm + (size_t)(n0 + (wave * 4 + 1) * 16 + rowInChunk) * ldb + kOff8;
    const __hip_bfloat16* bSrc2 = Bm + (size_t)(n0 + (wave * 4 + 2) * 16 + rowInChunk) * ldb + kOff8;
    const __hip_bfloat16* bSrc3 = Bm + (size_t)(n0 + (wave * 4 + 3) * 16 + rowInChunk) * ldb + kOff8;

    const int wSlot = (((lane & 3) + ((lane >> 3) & 3)) & 3) * 8;
    const int aW0 = (wave * 2 + 0) * 512 + rowInChunk * 32 + wSlot;
    const int aW1 = aW0 + 512;
    const int bW0 = (wave * 4 + 0) * 512 + rowInChunk * 32 + wSlot;
    const int bW1 = bW0 + 512;
    const int bW2 = bW0 + 1024;
    const int bW3 = bW0 + 1536;

    const int rSlot = ((((lane >> 4) + (((lane & 15) >> 1) & 3)) & 3)) * 8;
    const int rRow  = lane & 15;

    floatx4 acc[4][8];
    const floatx4 zero4 = {0.f, 0.f, 0.f, 0.f};
    #pragma unroll
    for (int i = 0; i < 4; i++)
        #pragma unroll
        for (int j = 0; j < 8; j++) acc[i][j] = zero4;

    int4 aE0, aE1, bE0, bE1, bE2, bE3;   // even stages
    int4 aO0, aO1, bO0, bO1, bO2, bO3;   // odd stages

    aE0 = *(const int4*)aSrc0; aE1 = *(const int4*)aSrc1;
    bE0 = *(const int4*)bSrc0; bE1 = *(const int4*)bSrc1;
    bE2 = *(const int4*)bSrc2; bE3 = *(const int4*)bSrc3;
    aSrc0 += BK; aSrc1 += BK; bSrc0 += BK; bSrc1 += BK; bSrc2 += BK; bSrc3 += BK;
    aO0 = *(const int4*)aSrc0; aO1 = *(const int4*)aSrc1;
    bO0 = *(const int4*)bSrc0; bO1 = *(const int4*)bSrc1;
    bO2 = *(const int4*)bSrc2; bO3 = *(const int4*)bSrc3;
    aSrc0 += BK; aSrc1 += BK; bSrc0 += BK; bSrc1 += BK; bSrc2 += BK; bSrc3 += BK;

    *(int4*)(&As[0][aW0]) = aE0;
    *(int4*)(&As[0][aW1]) = aE1;
    *(int4*)(&Bs[0][bW0]) = bE0;
    *(int4*)(&Bs[0][bW1]) = bE1;
    *(int4*)(&Bs[0][bW2]) = bE2;
    *(int4*)(&Bs[0][bW3]) = bE3;
    wg_barrier_lds();

    for (int kt = 0; kt < kIters; kt += 2) {
        const bool more = (kt + 2 < kIters);

        {   // u = 0
            bf16x8 af[4], bfr[8];
            #pragma unroll
            for (int mi = 0; mi < 4; mi++)
                af[mi] = *(const bf16x8*)(&As[0][(wi * 64 + mi * 16 + rRow) * BK + rSlot]);
            #pragma unroll
            for (int nj = 0; nj < 8; nj++)
                bfr[nj] = *(const bf16x8*)(&Bs[0][(wj * 128 + nj * 16 + rRow) * BK + rSlot]);

            if (more) {
                aE0 = *(const int4*)aSrc0; aE1 = *(const int4*)aSrc1;
                bE0 = *(const int4*)bSrc0; bE1 = *(const int4*)bSrc1;
                bE2 = *(const int4*)bSrc2; bE3 = *(const int4*)bSrc3;
                aSrc0 += BK; aSrc1 += BK; bSrc0 += BK; bSrc1 += BK; bSrc2 += BK; bSrc3 += BK;
            }
            *(int4*)(&As[1][aW0]) = aO0;
            *(int4*)(&As[1][aW1]) = aO1;
            *(int4*)(&Bs[1][bW0]) = bO0;
            *(int4*)(&Bs[1][bW1]) = bO1;
            *(int4*)(&Bs[1][bW2]) = bO2;
            *(int4*)(&Bs[1][bW3]) = bO3;

            #pragma unroll
            for (int mi = 0; mi < 4; mi++)
                #pragma unroll
                for (int nj = 0; nj < 8; nj++)
                    acc[mi][nj] = __builtin_amdgcn_mfma_f32_16x16x32_bf16(af[mi], bfr[nj], acc[mi][nj], 0, 0, 0);

            wg_barrier_lds();
        }

        {   // u = 1
            bf16x8 af[4], bfr[8];
            #pragma unroll
            for (int mi = 0; mi < 4; mi++)
                af[mi] = *(const bf16x8*)(&As[1][(wi * 64 + mi * 16 + rRow) * BK + rSlot]);
            #pragma unroll
            for (int nj = 0; nj < 8; nj++)
                bfr[nj] = *(const bf16x8*)(&Bs[1][(wj * 128 + nj * 16 + rRow) * BK + rSlot]);

            if (more) {
                aO0 = *(const int4*)aSrc0; aO1 = *(const int4*)aSrc1;
                bO0 = *(const int4*)bSrc0; bO1 = *(const int4*)bSrc1;
                bO2 = *(const int4*)bSrc2; bO3 = *(const int4*)bSrc3;
                aSrc0 += BK; aSrc1 += BK; bSrc0 += BK; bSrc1 += BK; bSrc2 += BK; bSrc3 += BK;
                *(int4*)(&As[0][aW0]) = aE0;
                *(int4*)(&As[0][aW1]) = aE1;
                *(int4*)(&Bs[0][bW0]) = bE0;
                *(int4*)(&Bs[0][bW1]) = bE1;
                *(int4*)(&Bs[0][bW2]) = bE2;
                *(int4*)(&Bs[0][bW3]) = bE3;
            }

            #pragma unroll
            for (int mi = 0; mi < 4; mi++)
                #pragma unroll
                for (int nj = 0; nj < 8; nj++)
                    acc[mi][nj] = __builtin_amdgcn_mfma_f32_16x16x32_bf16(af[mi], bfr[nj], acc[mi][nj], 0, 0, 0);

            wg_barrier_lds();
        }
    }

    // epilogue: elu + bias, bf16 store to h2f layout [(b)][n*32+c]
    #pragma unroll
    for (int mi = 0; mi < 4; mi++) {
        #pragma unroll
        for (int nj = 0; nj < 8; nj++) {
            #pragma unroll
            for (int r = 0; r < 4; r++) {
                const int row = m0 + wi * 64 + mi * 16 + (lane >> 4) * 4 + r;
                const int col = n0 + wj * 128 + nj * 16 + (lane & 15);
                if (row < NREAL) {
                    const int c = col & 31, b = col >> 5;
                    const float t = elu_f(acc[mi][nj][r] + bias[c]);
                    outH[(size_t)b * KFC + row * 32 + c] = __float2bfloat16(t);
                }
            }
        }
    }
}

// ---------------------------------------------------------------------------
// convXA: x -> Xbf row-major [1024][896] bf16 (zero k-pad)
//         a -> Ar row-major [896][896] bf16 (zero pad both dims)
// ---------------------------------------------------------------------------
__global__ void convXA(const float* __restrict__ x, const float* __restrict__ a,
                       __hip_bfloat16* __restrict__ Xbf, __hip_bfloat16* __restrict__ Ar)
{
    int idx = blockIdx.x * 256 + threadIdx.x;
    if (idx < BATCH * NPAD) {
        const int m = idx % NPAD, b = idx / NPAD;
        const float v = (m < NREAL) ? x[(size_t)b * NREAL + m] : 0.f;
        Xbf[idx] = __float2bfloat16(v);
    } else {
        idx -= BATCH * NPAD;
        if (idx < NPAD * NPAD) {
            const int m = idx % NPAD, n = idx / NPAD;
            const float v = (m < NREAL && n < NREAL) ? a[(size_t)n * NREAL + m] : 0.f;
            Ar[idx] = __float2bfloat16(v);
        }
    }
}

// wf1 [25088][512] fp32 -> Wt row-major bf16 [512][25088]
__global__ void convW(const float* __restrict__ wf1, __hip_bfloat16* __restrict__ Wt) {
    __shared__ float tile[32][33];
    const int k0 = blockIdx.x * 32, h0 = blockIdx.y * 32;
    const int tx = threadIdx.x, ty = threadIdx.y;  // (32,8)
    #pragma unroll
    for (int i = 0; i < 4; i++)
        tile[ty * 4 + i][tx] = wf1[(size_t)(k0 + ty * 4 + i) * HDIM + h0 + tx];
    __syncthreads();
    #pragma unroll
    for (int i = 0; i < 4; i++)
        Wt[(size_t)(h0 + ty * 4 + i) * KFC + k0 + tx] = __float2bfloat16(tile[tx][ty * 4 + i]);
}

// ---------------------------------------------------------------------------
// Layer-1 fused pointwise (r5-proven): reduce KS_G1 Y partials, then
// Tt[(b*32+c)][m] = sum_c1 elu(Y[b][m]*w1[c1]+b1[c1])*W2[c1][c]  (row-major)
// ---------------------------------------------------------------------------
__global__ void layer1_fuse(const float* __restrict__ Ypart,
                            const float* __restrict__ w1, const float* __restrict__ b1,
                            const float* __restrict__ w2,
                            __hip_bfloat16* __restrict__ Tt)
{
    __shared__ __align__(16) float sW2[C1D * C2D];
    __shared__ float sw1[C1D], sb1[C1D];
    const int tid = threadIdx.x;                 // 128 threads
    for (int i = tid; i < C1D * C2D; i += 128) sW2[i] = w2[i];
    if (tid < C1D) { sw1[tid] = w1[tid]; sb1[tid] = b1[tid]; }
    __syncthreads();

    const int m = blockIdx.x * 128 + tid;        // 0..895
    const int b = blockIdx.y;
    float y = 0.f;
    #pragma unroll
    for (int z = 0; z < KS_G1; z++)
        y += Ypart[(size_t)z * (BATCH * NPAD) + (size_t)b * NPAD + m];

    float h[C1D];
    #pragma unroll
    for (int c1 = 0; c1 < C1D; c1++) h[c1] = elu_f(y * sw1[c1] + sb1[c1]);

    float4 t4[8];
    #pragma unroll
    for (int q = 0; q < 8; q++) t4[q] = make_float4(0.f, 0.f, 0.f, 0.f);
    #pragma unroll
    for (int c1 = 0; c1 < C1D; c1++) {
        const float hv = h[c1];
        const float4* row = (const float4*)(sW2 + c1 * C2D);
        #pragma unroll
        for (int q = 0; q < 8; q++) {
            const float4 w = row[q];
            t4[q].x += hv * w.x; t4[q].y += hv * w.y;
            t4[q].z += hv * w.z; t4[q].w += hv * w.w;
        }
    }
    const float* tf = (const float*)t4;
    #pragma unroll
    for (int c = 0; c < C2D; c++)
        Tt[((size_t)(b * 32 + c)) * NPAD + m] = __float2bfloat16(tf[c]);
}

// ---------------------------------------------------------------------------
// fc1 reduce (split-K partials) + relu + fc2 + softmax, fused.
// ---------------------------------------------------------------------------
__global__ void fc2_softmax(const float* __restrict__ part, const float* __restrict__ bf1,
                            const float* __restrict__ wf2, const float* __restrict__ bf2,
                            float* __restrict__ out)
{
    __shared__ float sW[HDIM * NCLS];
    __shared__ float sb[NCLS];
    const int tid = threadIdx.x;                 // 256
    for (int i = tid; i < HDIM * NCLS; i += 256) sW[i] = wf2[i];
    if (tid < NCLS) sb[tid] = bf2[tid];
    __syncthreads();

    const int lane = tid & 63, wave = tid >> 6;
    const int b = blockIdx.x * 4 + wave;

    float acc[NCLS];
    #pragma unroll
    for (int c = 0; c < NCLS; c++) acc[c] = 0.f;
    #pragma unroll
    for (int q = 0; q < 8; q++) {
        const int h = q * 64 + lane;
        float hv = bf1[h];
        #pragma unroll
        for (int z = 0; z < KS_FC; z++)
            hv += part[(size_t)z * (BATCH * HDIM) + (size_t)b * HDIM + h];
        hv = hv > 0.f ? hv : 0.f;
        #pragma unroll
        for (int c = 0; c < NCLS; c++) acc[c] += hv * sW[h * NCLS + c];
    }
    #pragma unroll
    for (int c = 0; c < NCLS; c++) {
        #pragma unroll
        for (int off = 32; off >= 1; off >>= 1) acc[c] += __shfl_down(acc[c], off);
    }
    if (lane == 0) {
        float mx = -1e30f;
        #pragma unroll
        for (int c = 0; c < NCLS; c++) { acc[c] += sb[c]; mx = fmaxf(mx, acc[c]); }
        float e[NCLS], s = 0.f;
        #pragma unroll
        for (int c = 0; c < NCLS; c++) { e[c] = __expf(acc[c] - mx); s += e[c]; }
        const float inv = 1.f / s;
        #pragma unroll
        for (int c = 0; c < NCLS; c++) out[(size_t)b * NCLS + c] = e[c] * inv;
    }
}

// ---------------------------------------------------------------------------
// Workspace layout (peak ~113.5 MB)
//   h2f   [0,          51380224)  bf16 1024x25088  (written G3, read G4)
//     Ypart [0, 25690112) f32 7x1024x896 — overlay, dead before G3
//   Tt    [51380224,  110100480)  bf16 32768x896   (dead after G3)
//     Wt   [51380224, 77070336)   bf16 512x25088 — overlay after G3
//     part [77070336, 106430464)  f32 14x1024x512 — overlay after G3
//   Ar    [110100480, 111706112)  bf16 896x896
//   Xbf   [111706112, 113541120)  bf16 1024x896
// ---------------------------------------------------------------------------
extern "C" void kernel_launch(void* const* d_in, const int* in_sizes, int n_in,
                              void* d_out, int out_size, void* d_ws, size_t ws_size,
                              hipStream_t stream)
{
    const float* x   = (const float*)d_in[0];
    const float* a   = (const float*)d_in[1];
    const float* w1  = (const float*)d_in[2];
    const float* b1  = (const float*)d_in[3];
    const float* w2  = (const float*)d_in[4];
    const float* b2  = (const float*)d_in[5];
    const float* wf1 = (const float*)d_in[6];
    const float* bf1 = (const float*)d_in[7];
    const float* wf2 = (const float*)d_in[8];
    const float* bf2 = (const float*)d_in[9];
    float* out = (float*)d_out;

    char* ws = (char*)d_ws;
    __hip_bfloat16* h2f  = (__hip_bfloat16*)(ws + 0);
    float*          Ypart= (float*)(ws + 0);                  // overlay (pre-G3)
    __hip_bfloat16* Tt   = (__hip_bfloat16*)(ws + 51380224);
    __hip_bfloat16* Wt   = (__hip_bfloat16*)(ws + 51380224);  // overlay (post-G3)
    float*          part = (float*)(ws + 77070336);           // overlay (post-G3)
    __hip_bfloat16* Ar   = (__hip_bfloat16*)(ws + 110100480);
    __hip_bfloat16* Xbf  = (__hip_bfloat16*)(ws + 111706112);

    // 1) convert x and a (row-major bf16, zero-padded)
    convXA<<<(BATCH * NPAD + NPAD * NPAD + 255) / 256, 256, 0, stream>>>(x, a, Xbf, Ar);

    // 2) G1: Ypart[z][b][n] partials (split-K=7 -> 392 blocks, 4 iters)
    gemm_bt<2><<<dim3(NPAD / 128, BATCH / 128, KS_G1), 256, 0, stream>>>(
        Xbf, NPAD, Ar, NPAD, (NPAD / KS_G1) / BK, NPAD / KS_G1,
        (size_t)BATCH * NPAD, Ypart, NPAD);

    // 3) layer-1 pointwise + @W2 -> Tt row-major
    layer1_fuse<<<dim3(NPAD / 128, BATCH), 128, 0, stream>>>(Ypart, w1, b1, w2, Tt);

    // 4) G3 (wide): h2 = elu(A @ T + b2)  (M=896, N=32768 -> 128x7 = 896 blocks, 28 iters)
    gemm_w<<<dim3((BATCH * 32) / 256, NPAD / 128, 1), 256, 0, stream>>>(
        Ar, NPAD, Tt, NPAD, NPAD / BK, h2f, b2);

    // 5) wf1 -> Wt row-major (into dead-Tt region)
    convW<<<dim3(KFC / 32, HDIM / 32), dim3(32, 8), 0, stream>>>(wf1, Wt);

    // 6) G4: fc1 partials, split-K=14 (448 blocks, 56 iters)
    gemm_bt<2><<<dim3(HDIM / 128, BATCH / 128, KS_FC), 256, 0, stream>>>(
        h2f, KFC, Wt, KFC, (KFC / KS_FC) / BK, KFC / KS_FC,
        (size_t)BATCH * HDIM, part, HDIM);

    // 7) fc1 reduce + relu + fc2 + softmax
    fc2_softmax<<<BATCH / 4, 256, 0, stream>>>(part, bf1, wf2, bf2, out);
}